// Round 1
// baseline (16993.242 us; speedup 1.0000x reference)
//
#include <hip/hip_runtime.h>
#include <math.h>

// ---------------- problem constants ----------------
constexpr int Bq   = 2;
constexpr int Lq   = 2048;
constexpr int Mq   = 2048;
constexpr int Dq   = 1024;
constexpr int DFFq = 4096;
constexpr int Hq   = 16;
constexpr int DHq  = 64;
constexpr int Vq   = 8192;
constexpr int NLq  = 4;
constexpr int Wwin = 512;          // window W
constexpr int NCVq = 64;           // compressed chunks total
constexpr int HWLEN = Wwin + Lq;   // 2560

// ---------------- workspace layout (float offsets) ----------------
constexpr size_t OFF_H    = 0;
constexpr size_t OFF_A    = OFF_H    + (size_t)Bq*Lq*Dq;       // 4,194,304
constexpr size_t OFF_ATT  = OFF_A    + (size_t)Bq*Lq*Dq;
constexpr size_t OFF_Q    = OFF_ATT  + (size_t)Bq*Lq*Dq;
constexpr size_t OFF_HW   = OFF_Q    + (size_t)Bq*Lq*Dq;
constexpr size_t OFF_KW   = OFF_HW   + (size_t)Bq*HWLEN*Dq;    // 5,242,880
constexpr size_t OFF_VW   = OFF_KW   + (size_t)Bq*HWLEN*Dq;
constexpr size_t OFF_FF   = OFF_VW   + (size_t)Bq*HWLEN*Dq;
constexpr size_t OFF_COMP = OFF_FF   + (size_t)Bq*Lq*DFFq;     // 16,777,216
constexpr size_t OFF_KC   = OFF_COMP + (size_t)Bq*NCVq*Dq;
constexpr size_t OFF_VC   = OFF_KC   + (size_t)Bq*NCVq*Dq;
constexpr size_t OFF_SCC  = OFF_VC   + (size_t)Bq*NCVq*Dq;
constexpr size_t OFF_SCH  = OFF_SCC  + (size_t)Bq*Mq*16;
constexpr size_t OFF_PWIN = OFF_SCH  + (size_t)Bq*Lq*16;
constexpr size_t OFF_KPE  = OFF_PWIN + (size_t)Wwin*Dq;
constexpr size_t OFF_PW   = OFF_KPE  + (size_t)NCVq*Dq;
constexpr size_t OFF_PC   = OFF_PW   + (size_t)Wwin*Dq;
constexpr size_t WS_FLOATS= OFF_PC   + (size_t)NCVq*Dq;        // ~51.0M floats (~204 MiB)

// ---------------- embed ----------------
__global__ __launch_bounds__(256) void embed_kernel(const int* __restrict__ x,
                                                    const float* __restrict__ emb,
                                                    float* __restrict__ h) {
  int i = blockIdx.x * 256 + threadIdx.x;           // over B*L*D
  int tok = i >> 10;
  int d = i & 1023;
  h[i] = emb[(size_t)x[tok] * Dq + d] * 32.0f;      // sqrt(1024) = 32
}

// ---------------- sinusoidal position tables ----------------
__global__ __launch_bounds__(256) void posemb_kernel(float* __restrict__ pwin,
                                                     float* __restrict__ kpe) {
  int i = blockIdx.x * 256 + threadIdx.x;           // over (512+64)*1024
  int row = i >> 10, col = i & 1023;
  int ii = col & 511;
  bool is_cos = col >= 512;
  float invf = (float)exp(-((double)(2 * ii) / 1024.0) * log(10000.0));
  float* dst; float pos;
  if (row < Wwin) { dst = pwin + (size_t)row * Dq + col; pos = (float)(Wwin - 1 - row); }
  else { dst = kpe + (size_t)(row - Wwin) * Dq + col; pos = (float)(NCVq - 1 - (row - Wwin)); }
  float ang = pos * invf;
  *dst = is_cos ? cosf(ang) : sinf(ang);
}

// ---------------- generic tiled fp32 GEMM ----------------
// C(M,N) = A(M,K) @ B(K,N)          (BT=0)
// C(M,N) = A(M,K) @ B(N,K)^T        (BT=1)
// EPI: 0 none, 1 +bias, 2 gelu(.+bias)
// Requirements: M%64==0, K%16==0, N%4==0 (guards handle N<64 tiles).
template<int BT, int EPI>
__global__ __launch_bounds__(256) void gemm_kernel(const float* __restrict__ A,
                                                   const float* __restrict__ Bm,
                                                   const float* __restrict__ bias,
                                                   float* __restrict__ C,
                                                   int M, int N, int K) {
  __shared__ float As[16][64];
  __shared__ float Bs[16][64];
  const int tid = threadIdx.x;
  const int tx = tid & 15;
  const int ty = tid >> 4;
  const int m0 = blockIdx.y * 64;
  const int n0 = blockIdx.x * 64;
  const int ar = tid >> 2;
  const int ak = (tid & 3) << 2;
  float acc[4][4] = {};
  for (int k0 = 0; k0 < K; k0 += 16) {
    float4 av = *(const float4*)(A + (size_t)(m0 + ar) * K + (k0 + ak));
    As[ak + 0][ar] = av.x; As[ak + 1][ar] = av.y;
    As[ak + 2][ar] = av.z; As[ak + 3][ar] = av.w;
    if (BT == 0) {
      const int bk = tid >> 4;
      const int bc = (tid & 15) << 2;
      float4 bv = make_float4(0.f, 0.f, 0.f, 0.f);
      if (n0 + bc < N) bv = *(const float4*)(Bm + (size_t)(k0 + bk) * N + (n0 + bc));
      Bs[bk][bc + 0] = bv.x; Bs[bk][bc + 1] = bv.y;
      Bs[bk][bc + 2] = bv.z; Bs[bk][bc + 3] = bv.w;
    } else {
      const int c = tid >> 2;
      const int kk = (tid & 3) << 2;
      float4 bv = make_float4(0.f, 0.f, 0.f, 0.f);
      if (n0 + c < N) bv = *(const float4*)(Bm + (size_t)(n0 + c) * K + (k0 + kk));
      Bs[kk + 0][c] = bv.x; Bs[kk + 1][c] = bv.y;
      Bs[kk + 2][c] = bv.z; Bs[kk + 3][c] = bv.w;
    }
    __syncthreads();
#pragma unroll
    for (int k = 0; k < 16; ++k) {
      float4 a4 = *(const float4*)&As[k][ty << 2];
      float4 b4 = *(const float4*)&Bs[k][tx << 2];
      float aa[4] = {a4.x, a4.y, a4.z, a4.w};
      float bb[4] = {b4.x, b4.y, b4.z, b4.w};
#pragma unroll
      for (int i = 0; i < 4; ++i)
#pragma unroll
        for (int j = 0; j < 4; ++j) acc[i][j] += aa[i] * bb[j];
    }
    __syncthreads();
  }
  const int cbase = n0 + (tx << 2);
  if (cbase < N) {
#pragma unroll
    for (int i = 0; i < 4; ++i) {
      const int r = m0 + (ty << 2) + i;
      float4 o;
      float* op = &o.x;
#pragma unroll
      for (int j = 0; j < 4; ++j) {
        float v = acc[i][j];
        if (EPI >= 1) v += bias[cbase + j];
        if (EPI == 2) v = 0.5f * v * (1.0f + erff(v * 0.70710678118654752f));
        op[j] = v;
      }
      *(float4*)(C + (size_t)r * N + cbase) = o;
    }
  }
}

// ---------------- LayerNorm (row length 1024), optional residual, in-place safe ----------------
__global__ __launch_bounds__(256) void ln_kernel(const float* __restrict__ x,
                                                 const float* __restrict__ res,
                                                 const float* __restrict__ g,
                                                 const float* __restrict__ b,
                                                 float* __restrict__ out) {
  __shared__ float sm[4];
  const int row = blockIdx.x;
  const int t = threadIdx.x;
  const float* xp = x + (size_t)row * Dq;
  float v[4];
#pragma unroll
  for (int i = 0; i < 4; ++i) v[i] = xp[t + 256 * i];
  if (res) {
    const float* rp = res + (size_t)row * Dq;
#pragma unroll
    for (int i = 0; i < 4; ++i) v[i] += rp[t + 256 * i];
  }
  float s = v[0] + v[1] + v[2] + v[3];
#pragma unroll
  for (int off = 32; off > 0; off >>= 1) s += __shfl_down(s, off);
  if ((t & 63) == 0) sm[t >> 6] = s;
  __syncthreads();
  const float mu = (sm[0] + sm[1] + sm[2] + sm[3]) * (1.0f / Dq);
  __syncthreads();
  float s2 = 0.f;
#pragma unroll
  for (int i = 0; i < 4; ++i) { float d = v[i] - mu; s2 += d * d; }
#pragma unroll
  for (int off = 32; off > 0; off >>= 1) s2 += __shfl_down(s2, off);
  if ((t & 63) == 0) sm[t >> 6] = s2;
  __syncthreads();
  const float var = (sm[0] + sm[1] + sm[2] + sm[3]) * (1.0f / Dq);
  const float rstd = rsqrtf(var + 1e-5f);
  float* op = out + (size_t)row * Dq;
#pragma unroll
  for (int i = 0; i < 4; ++i) {
    int c = t + 256 * i;
    op[c] = (v[i] - mu) * rstd * g[c] + b[c];
  }
}

// ---------------- compress: softmax over chunk (S=64) then weighted value sum ----------------
// grid: B*64*H blocks, 64 threads. comp slot c<32 <- cache chunk c ; c>=32 <- h chunk c-32
__global__ __launch_bounds__(64) void compress_kernel(const float* __restrict__ scc,  // (B*2048,16)
                                                      const float* __restrict__ sch,  // (B*2048,16)
                                                      const float* __restrict__ cache_l, // (B,2048,1024)
                                                      const float* __restrict__ h,       // (B,2048,1024)
                                                      float* __restrict__ comp) {       // (B,64,1024)
  const int bi = blockIdx.x;
  const int head = bi & 15;
  const int c = (bi >> 4) & 63;
  const int b = bi >> 10;
  const bool from_cache = c < 32;
  const int cc = from_cache ? c : c - 32;
  const float* logits = (from_cache ? scc : sch) + (size_t)(b * 2048 + cc * 64) * 16 + head;
  const float* seq = (from_cache ? cache_l : h) + (size_t)(b * 2048 + cc * 64) * Dq + head * 64;
  __shared__ float wsm[64];
  const int t = threadIdx.x;
  wsm[t] = logits[(size_t)t * 16];
  __syncthreads();
  float mx = -1e30f;
#pragma unroll 8
  for (int s = 0; s < 64; ++s) mx = fmaxf(mx, wsm[s]);
  float sum = 0.f;
#pragma unroll 8
  for (int s = 0; s < 64; ++s) sum += expf(wsm[s] - mx);
  float myw = expf(wsm[t] - mx) / sum;
  __syncthreads();
  wsm[t] = myw;
  __syncthreads();
  float acc = 0.f;
#pragma unroll 4
  for (int s = 0; s < 64; ++s) acc += wsm[s] * seq[(size_t)s * Dq + t];
  comp[(size_t)(b * 64 + c) * Dq + head * 64 + t] = acc;
}

// ---------------- build hw = concat(cache[:, -W:], h) ----------------
__global__ __launch_bounds__(256) void hwbuild_kernel(const float* __restrict__ cache_l,
                                                      const float* __restrict__ h,
                                                      float* __restrict__ hw) {
  int i = blockIdx.x * 256 + threadIdx.x;           // over B*2560*256 float4
  const int D4 = Dq / 4;
  int d4 = i % D4;
  int r = (i / D4) % HWLEN;
  int b = i / (HWLEN * D4);
  const float4* src;
  if (r < Wwin) src = (const float4*)(cache_l + (size_t)(b * Mq + (Mq - Wwin) + r) * Dq) + d4;
  else          src = (const float4*)(h + (size_t)(b * Lq + (r - Wwin)) * Dq) + d4;
  ((float4*)hw)[i] = *src;
}

// ---------------- fused long-short attention ----------------
// grid: B*H*64 blocks (32 queries each), 256 threads
__global__ __launch_bounds__(256) void attn_kernel(const float* __restrict__ q,   // (B*L, D)
                                                   const float* __restrict__ kw,  // (B*2560, D)
                                                   const float* __restrict__ vw,
                                                   const float* __restrict__ kc,  // (B*64, D)
                                                   const float* __restrict__ vc,
                                                   const float* __restrict__ Pw,  // (512, D)
                                                   const float* __restrict__ Pc,  // (64, D)
                                                   const float* __restrict__ rw,  // (H,DH)
                                                   const float* __restrict__ rr,
                                                   float* __restrict__ att) {     // (B*L, D)
  __shared__ float qws[32][64];
  __shared__ float qrs[32][64];
  __shared__ float sc[32][580];        // 512 window + 64 compressed
  __shared__ float ksf[64 * 64];       // staging, XOR-swizzled rows
  const int blk = blockIdx.x;
  const int qblk = blk & 63;
  const int hh = (blk >> 6) & 15;
  const int b = blk >> 10;
  const int qbase = qblk * 32;
  const int qc = qblk >> 1;
  const int t = threadIdx.x;
  const int hoff = hh * 64;

  // load q, build qw/qr
#pragma unroll
  for (int i = 0; i < 8; ++i) {
    int e = t + 256 * i;
    int qi = e >> 6, d = e & 63;
    float qv = q[(size_t)(b * Lq + qbase + qi) * Dq + hoff + d] * 0.125f;
    qws[qi][d] = qv + rw[hoff + d];
    qrs[qi][d] = qv + rr[hoff + d];
  }
  __syncthreads();

  const int eq = t >> 6;   // 0..3
  const int ed = t & 63;   // 0..63

  // ---- Phase A: window positional bias sc[qi][j] = qr . Pw[j]
  for (int cb = 0; cb < 8; ++cb) {
#pragma unroll
    for (int i = 0; i < 16; ++i) {
      int e = t + 256 * i;
      int jj = e >> 6, d = e & 63;
      ksf[jj * 64 + (d ^ ((jj & 7) << 2))] = Pw[(size_t)(cb * 64 + jj) * Dq + hoff + d];
    }
    __syncthreads();
#pragma unroll
    for (int rs = 0; rs < 8; ++rs) {
      int qi = eq + 4 * rs;
      int jj = ed;
      float dot = 0.f;
#pragma unroll
      for (int d0 = 0; d0 < 64; d0 += 4) {
        float4 qv = *(const float4*)&qrs[qi][d0];
        float4 kv = *(const float4*)&ksf[jj * 64 + (d0 ^ ((jj & 7) << 2))];
        dot += qv.x * kv.x + qv.y * kv.y + qv.z * kv.z + qv.w * kv.w;
      }
      sc[qi][cb * 64 + jj] = dot;
    }
    __syncthreads();
  }

  // ---- Phase B: window key dots sc[qi][j] += qw . kw[l+1+j]
  for (int ci = 0; ci < 9; ++ci) {
    const int khw0 = qbase + 1 + ci * 64;
#pragma unroll
    for (int i = 0; i < 16; ++i) {
      int e = t + 256 * i;
      int kk = e >> 6, d = e & 63;
      int khw = khw0 + kk; if (khw > HWLEN - 1) khw = HWLEN - 1;
      ksf[kk * 64 + (d ^ ((kk & 7) << 2))] = kw[(size_t)(b * HWLEN + khw) * Dq + hoff + d];
    }
    __syncthreads();
#pragma unroll
    for (int rs = 0; rs < 8; ++rs) {
      int qi = eq + 4 * rs;
      int kk = ed;
      int j = ci * 64 + kk - qi;
      if (j >= 0 && j < 512) {
        float dot = 0.f;
#pragma unroll
        for (int d0 = 0; d0 < 64; d0 += 4) {
          float4 qv = *(const float4*)&qws[qi][d0];
          float4 kv = *(const float4*)&ksf[kk * 64 + (d0 ^ ((kk & 7) << 2))];
          dot += qv.x * kv.x + qv.y * kv.y + qv.z * kv.z + qv.w * kv.w;
        }
        sc[qi][j] += dot;
      }
    }
    __syncthreads();
  }

  // ---- Phase C1: compressed key dots
#pragma unroll
  for (int i = 0; i < 16; ++i) {
    int e = t + 256 * i;
    int cc = e >> 6, d = e & 63;
    ksf[cc * 64 + (d ^ ((cc & 7) << 2))] = kc[(size_t)(b * 64 + cc) * Dq + hoff + d];
  }
  __syncthreads();
#pragma unroll
  for (int rs = 0; rs < 8; ++rs) {
    int qi = eq + 4 * rs;
    int cc = ed;
    float dot = 0.f;
#pragma unroll
    for (int d0 = 0; d0 < 64; d0 += 4) {
      float4 qv = *(const float4*)&qws[qi][d0];
      float4 kv = *(const float4*)&ksf[cc * 64 + (d0 ^ ((cc & 7) << 2))];
      dot += qv.x * kv.x + qv.y * kv.y + qv.z * kv.z + qv.w * kv.w;
    }
    sc[qi][512 + cc] = dot;
  }
  __syncthreads();
  // ---- Phase C2: compressed positional bias + causal mask
#pragma unroll
  for (int i = 0; i < 16; ++i) {
    int e = t + 256 * i;
    int cc = e >> 6, d = e & 63;
    int pidx = 31 - qc + cc;
    pidx = pidx < 0 ? 0 : (pidx > 63 ? 63 : pidx);
    ksf[cc * 64 + (d ^ ((cc & 7) << 2))] = Pc[(size_t)pidx * Dq + hoff + d];
  }
  __syncthreads();
#pragma unroll
  for (int rs = 0; rs < 8; ++rs) {
    int qi = eq + 4 * rs;
    int cc = ed;
    float dot = 0.f;
#pragma unroll
    for (int d0 = 0; d0 < 64; d0 += 4) {
      float4 qv = *(const float4*)&qrs[qi][d0];
      float4 kv = *(const float4*)&ksf[cc * 64 + (d0 ^ ((cc & 7) << 2))];
      dot += qv.x * kv.x + qv.y * kv.y + qv.z * kv.z + qv.w * kv.w;
    }
    float vvv = sc[qi][512 + cc] + dot;
    sc[qi][512 + cc] = (cc >= qc + 32) ? -1e30f : vvv;
  }
  __syncthreads();

  // ---- Phase D: softmax over 576 per query row (8 lanes per row)
  {
    const int row = t >> 3;
    const int sub = t & 7;
    float m = -1e30f;
    for (int k = 0; k < 72; ++k) m = fmaxf(m, sc[row][sub + 8 * k]);
#pragma unroll
    for (int off = 1; off < 8; off <<= 1) m = fmaxf(m, __shfl_xor(m, off, 8));
    float ssum = 0.f;
    for (int k = 0; k < 72; ++k) ssum += expf(sc[row][sub + 8 * k] - m);
#pragma unroll
    for (int off = 1; off < 8; off <<= 1) ssum += __shfl_xor(ssum, off, 8);
    const float inv = 1.0f / ssum;
    for (int k = 0; k < 72; ++k) {
      int idx = sub + 8 * k;
      sc[row][idx] = expf(sc[row][idx] - m) * inv;
    }
  }
  __syncthreads();

  // ---- Phase E: out = P_win @ Vwin + P_comp @ Vcomp
  float acc[8] = {};
  const size_t vwbase = (size_t)b * HWLEN * Dq + hoff + ed;
  for (int j = 0; j < 512; ++j) {
#pragma unroll
    for (int rs = 0; rs < 8; ++rs) {
      int qi = eq + 4 * rs;
      acc[rs] += sc[qi][j] * vw[vwbase + (size_t)(qbase + qi + 1 + j) * Dq];
    }
  }
  const size_t vcbase = (size_t)b * 64 * Dq + hoff + ed;
  for (int cc = 0; cc < 64; ++cc) {
#pragma unroll
    for (int rs = 0; rs < 8; ++rs) {
      int qi = eq + 4 * rs;
      acc[rs] += sc[qi][512 + cc] * vc[vcbase + (size_t)cc * Dq];
    }
  }
#pragma unroll
  for (int rs = 0; rs < 8; ++rs) {
    int qi = eq + 4 * rs;
    att[(size_t)(b * Lq + qbase + qi) * Dq + hoff + ed] = acc[rs];
  }
}

// ---------------- log_softmax in place over rows of V=8192 ----------------
__global__ __launch_bounds__(256) void logsoftmax_kernel(float* __restrict__ out) {
  __shared__ float sm[4];
  const int row = blockIdx.x;
  float* p = out + (size_t)row * Vq;
  const int t = threadIdx.x;
  float v[32];
  float m = -1e30f;
#pragma unroll
  for (int i = 0; i < 32; ++i) { v[i] = p[t + 256 * i]; m = fmaxf(m, v[i]); }
#pragma unroll
  for (int off = 32; off > 0; off >>= 1) m = fmaxf(m, __shfl_xor(m, off));
  if ((t & 63) == 0) sm[t >> 6] = m;
  __syncthreads();
  m = fmaxf(fmaxf(sm[0], sm[1]), fmaxf(sm[2], sm[3]));
  __syncthreads();
  float s = 0.f;
#pragma unroll
  for (int i = 0; i < 32; ++i) s += expf(v[i] - m);
#pragma unroll
  for (int off = 32; off > 0; off >>= 1) s += __shfl_down(s, off);
  if ((t & 63) == 0) sm[t >> 6] = s;
  __syncthreads();
  const float lse = m + logf(sm[0] + sm[1] + sm[2] + sm[3]);
#pragma unroll
  for (int i = 0; i < 32; ++i) p[t + 256 * i] = v[i] - lse;
}

// ---------------- host orchestration ----------------
extern "C" void kernel_launch(void* const* d_in, const int* in_sizes, int n_in,
                              void* d_out, int out_size, void* d_ws, size_t ws_size,
                              hipStream_t stream) {
  if (ws_size < WS_FLOATS * sizeof(float)) return;  // insufficient scratch: fail loudly

  const int*   x        = (const int*)d_in[0];
  const float* cache    = (const float*)d_in[1];
  const float* emb      = (const float*)d_in[2];
  const float* out_bias = (const float*)d_in[3];
  const float* Wqw      = (const float*)d_in[4];
  const float* Wkw      = (const float*)d_in[5];
  const float* Wvw      = (const float*)d_in[6];
  const float* Wow      = (const float*)d_in[7];
  const float* w_dc     = (const float*)d_in[8];
  const float* b_dc     = (const float*)d_in[9];
  const float* Wr       = (const float*)d_in[10];
  const float* Wrc      = (const float*)d_in[11];
  const float* brc      = (const float*)d_in[12];
  const float* rw       = (const float*)d_in[13];
  const float* rr       = (const float*)d_in[14];
  const float* g1       = (const float*)d_in[15];
  const float* b1       = (const float*)d_in[16];
  const float* g2       = (const float*)d_in[17];
  const float* b2       = (const float*)d_in[18];
  const float* gd       = (const float*)d_in[19];
  const float* bd       = (const float*)d_in[20];
  const float* gw       = (const float*)d_in[21];
  const float* bw       = (const float*)d_in[22];
  const float* wf1      = (const float*)d_in[23];
  const float* bf1      = (const float*)d_in[24];
  const float* wf2      = (const float*)d_in[25];
  const float* bf2      = (const float*)d_in[26];

  float* ws   = (float*)d_ws;
  float* hbuf = ws + OFF_H;
  float* abuf = ws + OFF_A;
  float* attb = ws + OFF_ATT;
  float* qb   = ws + OFF_Q;
  float* hwb  = ws + OFF_HW;
  float* kwb  = ws + OFF_KW;
  float* vwb  = ws + OFF_VW;
  float* ffb  = ws + OFF_FF;
  float* comp = ws + OFF_COMP;
  float* kcb  = ws + OFF_KC;
  float* vcb  = ws + OFF_VC;
  float* scc  = ws + OFF_SCC;
  float* sch  = ws + OFF_SCH;
  float* pwin = ws + OFF_PWIN;
  float* kpe  = ws + OFF_KPE;
  float* Pwb  = ws + OFF_PW;
  float* Pcb  = ws + OFF_PC;
  float* outp = (float*)d_out;

  embed_kernel<<<(Bq * Lq * Dq) / 256, 256, 0, stream>>>(x, emb, hbuf);
  posemb_kernel<<<((Wwin + NCVq) * Dq) / 256, 256, 0, stream>>>(pwin, kpe);

  for (int l = 0; l < NLq; ++l) {
    const float* cache_l = cache + (size_t)l * Bq * Mq * Dq;
    const float* Wq_l  = Wqw + (size_t)l * Dq * Dq;
    const float* Wk_l  = Wkw + (size_t)l * Dq * Dq;
    const float* Wv_l  = Wvw + (size_t)l * Dq * Dq;
    const float* Wo_l  = Wow + (size_t)l * Dq * Dq;
    const float* wdc_l = w_dc + (size_t)l * Dq * 16;
    const float* bdc_l = b_dc + (size_t)l * 16;
    const float* Wr_l  = Wr  + (size_t)l * Dq * Dq;
    const float* Wrc_l = Wrc + (size_t)l * Dq * Dq;
    const float* brc_l = brc + (size_t)l * Dq;
    const float* rw_l  = rw  + (size_t)l * Hq * DHq;
    const float* rr_l  = rr  + (size_t)l * Hq * DHq;
    const float* g1_l  = g1 + (size_t)l * Dq;  const float* b1_l = b1 + (size_t)l * Dq;
    const float* g2_l  = g2 + (size_t)l * Dq;  const float* b2_l = b2 + (size_t)l * Dq;
    const float* gd_l  = gd + (size_t)l * Dq;  const float* bd_l = bd + (size_t)l * Dq;
    const float* gw_l  = gw + (size_t)l * Dq;  const float* bw_l = bw + (size_t)l * Dq;
    const float* wf1_l = wf1 + (size_t)l * Dq * DFFq;
    const float* bf1_l = bf1 + (size_t)l * DFFq;
    const float* wf2_l = wf2 + (size_t)l * DFFq * Dq;
    const float* bf2_l = bf2 + (size_t)l * Dq;

    // compression scores
    gemm_kernel<0, 1><<<dim3(1, 64), 256, 0, stream>>>(cache_l, wdc_l, bdc_l, scc, Bq * Mq, 16, Dq);
    gemm_kernel<0, 1><<<dim3(1, 64), 256, 0, stream>>>(hbuf, wdc_l, bdc_l, sch, Bq * Lq, 16, Dq);
    compress_kernel<<<Bq * 64 * Hq, 64, 0, stream>>>(scc, sch, cache_l, hbuf, comp);
    // compressed K/V
    gemm_kernel<0, 0><<<dim3(16, 2), 256, 0, stream>>>(comp, Wk_l, nullptr, kcb, Bq * NCVq, Dq, Dq);
    ln_kernel<<<Bq * NCVq, 256, 0, stream>>>(kcb, nullptr, gd_l, bd_l, kcb);
    gemm_kernel<0, 0><<<dim3(16, 2), 256, 0, stream>>>(comp, Wv_l, nullptr, vcb, Bq * NCVq, Dq, Dq);
    ln_kernel<<<Bq * NCVq, 256, 0, stream>>>(vcb, nullptr, gd_l, bd_l, vcb);
    // window K/V
    hwbuild_kernel<<<(Bq * HWLEN * (Dq / 4)) / 256, 256, 0, stream>>>(cache_l, hbuf, hwb);
    gemm_kernel<0, 0><<<dim3(16, 80), 256, 0, stream>>>(hwb, Wk_l, nullptr, kwb, Bq * HWLEN, Dq, Dq);
    ln_kernel<<<Bq * HWLEN, 256, 0, stream>>>(kwb, nullptr, gw_l, bw_l, kwb);
    gemm_kernel<0, 0><<<dim3(16, 80), 256, 0, stream>>>(hwb, Wv_l, nullptr, vwb, Bq * HWLEN, Dq, Dq);
    ln_kernel<<<Bq * HWLEN, 256, 0, stream>>>(vwb, nullptr, gw_l, bw_l, vwb);
    // Q and positional projections
    gemm_kernel<0, 0><<<dim3(16, 64), 256, 0, stream>>>(hbuf, Wq_l, nullptr, qb, Bq * Lq, Dq, Dq);
    gemm_kernel<0, 0><<<dim3(16, 8), 256, 0, stream>>>(pwin, Wr_l, nullptr, Pwb, Wwin, Dq, Dq);
    gemm_kernel<0, 1><<<dim3(16, 1), 256, 0, stream>>>(kpe, Wrc_l, brc_l, Pcb, NCVq, Dq, Dq);
    // fused attention
    attn_kernel<<<Bq * Hq * 64, 256, 0, stream>>>(qb, kwb, vwb, kcb, vcb, Pwb, Pcb, rw_l, rr_l, attb);
    // output projection + residual LN
    gemm_kernel<0, 0><<<dim3(16, 64), 256, 0, stream>>>(attb, Wo_l, nullptr, abuf, Bq * Lq, Dq, Dq);
    ln_kernel<<<Bq * Lq, 256, 0, stream>>>(hbuf, abuf, g1_l, b1_l, hbuf);
    // FFN
    gemm_kernel<0, 2><<<dim3(64, 64), 256, 0, stream>>>(hbuf, wf1_l, bf1_l, ffb, Bq * Lq, DFFq, Dq);
    gemm_kernel<0, 1><<<dim3(16, 64), 256, 0, stream>>>(ffb, wf2_l, bf2_l, abuf, Bq * Lq, Dq, DFFq);
    ln_kernel<<<Bq * Lq, 256, 0, stream>>>(hbuf, abuf, g2_l, b2_l, hbuf);
  }

  // LM head + log_softmax (in place in d_out)
  gemm_kernel<1, 1><<<dim3(Vq / 64, (Bq * Lq) / 64), 256, 0, stream>>>(hbuf, emb, out_bias, outp,
                                                                       Bq * Lq, Vq, Dq);
  logsoftmax_kernel<<<Bq * Lq, 256, 0, stream>>>(outp);
}